// Round 9
// baseline (268.550 us; speedup 1.0000x reference)
//
#include <hip/hip_runtime.h>

#define N_NODES 50000
#define PADROWS 50176   // 196*256, lets combine load A branchlessly (256-row tiles)
#define N_EDGES 600000
#define NPART 196   // ceil(50000/256)
#define MBLK2 196   // ceil(50000/256) row-blocks for 256-row combine tiles

using f32x2  = __attribute__((ext_vector_type(2))) float;
using f32x4  = __attribute__((ext_vector_type(4))) float;
using bf16x8 = __attribute__((ext_vector_type(8))) short;

__device__ inline ushort f2bf(float f) {
    uint32_t u = __builtin_bit_cast(uint32_t, f);
    uint32_t r = (u + 0x7FFFu + ((u >> 16) & 1u)) >> 16;
    return (ushort)r;
}
__device__ inline float bf2f(ushort h) {
    uint32_t u = ((uint32_t)h) << 16;
    return __builtin_bit_cast(float, u);
}

// ---------------------------------------------------------------- zero

__global__ void zero2_kernel(int* __restrict__ a, int* __restrict__ b) {
    int i = blockIdx.x * 256 + threadIdx.x;
    if (i < N_NODES) { a[i] = 0; b[i] = 0; }
}

// ---------------------------------------------------------------- CSR build

__global__ void count_kernel(const int* __restrict__ dst, int* __restrict__ cnt) {
    int e = blockIdx.x * blockDim.x + threadIdx.x;
    if (e < N_EDGES) atomicAdd(&cnt[dst[e]], 1);
}

__global__ void scan_part(const int* __restrict__ cnt, int* __restrict__ partials) {
    __shared__ int sm[256];
    int b = blockIdx.x, t = threadIdx.x;
    int i = b * 256 + t;
    sm[t] = (i < N_NODES) ? cnt[i] : 0;
    __syncthreads();
    for (int off = 128; off > 0; off >>= 1) {
        if (t < off) sm[t] += sm[t + off];
        __syncthreads();
    }
    if (t == 0) partials[b] = sm[0];
}

__global__ void scan_mid(const int* __restrict__ partials, int* __restrict__ offsets) {
    __shared__ int sm[256];
    int t = threadIdx.x;
    int v = (t < NPART) ? partials[t] : 0;
    sm[t] = v;
    __syncthreads();
    for (int off = 1; off < 256; off <<= 1) {
        int u = (t >= off) ? sm[t - off] : 0;
        __syncthreads();
        sm[t] += u;
        __syncthreads();
    }
    if (t < NPART) offsets[t] = sm[t] - v;   // exclusive prefix
}

__global__ void scan_final(const int* __restrict__ cnt, const int* __restrict__ offsets,
                           int* __restrict__ rowptr) {
    __shared__ int sm[256];
    int b = blockIdx.x, t = threadIdx.x;
    int i = b * 256 + t;
    int v = (i < N_NODES) ? cnt[i] : 0;
    sm[t] = v;
    __syncthreads();
    for (int off = 1; off < 256; off <<= 1) {
        int u = (t >= off) ? sm[t - off] : 0;
        __syncthreads();
        sm[t] += u;
        __syncthreads();
    }
    if (i < N_NODES) rowptr[i + 1] = sm[t] + offsets[b];
    if (i == 0) rowptr[0] = 0;
}

__global__ void fill_kernel(const int* __restrict__ src, const int* __restrict__ dst,
                            const int* __restrict__ rowptr, int* __restrict__ cursor,
                            int* __restrict__ col) {
    int e = blockIdx.x * blockDim.x + threadIdx.x;
    if (e < N_EDGES) {
        int d = dst[e];
        int pos = atomicAdd(&cursor[d], 1);
        col[rowptr[d] + pos] = src[e];
    }
}

// ---------------------------------------------------------------- prep: 3x wsplit + x cast, one launch

__device__ inline void wsplit_one(const float* __restrict__ Ws, const float* __restrict__ Wn,
                                  short* __restrict__ Wh, short* __restrict__ Wl,
                                  int nout, int idx) {
    int c = idx >> 8, k = idx & 255;
    float v = (k < 128) ? Ws[(size_t)k * nout + c] : Wn[(size_t)(k - 128) * nout + c];
    ushort hi = f2bf(v);
    Wh[idx] = (short)hi;
    Wl[idx] = (short)f2bf(v - bf2f(hi));
}

__global__ void prep_kernel(const float* __restrict__ Ws0, const float* __restrict__ Wn0,
                            const float* __restrict__ Ws1, const float* __restrict__ Wn1,
                            const float* __restrict__ Ws2, const float* __restrict__ Wn2,
                            const float* __restrict__ x,
                            short* __restrict__ W0h, short* __restrict__ W0l,
                            short* __restrict__ W1h, short* __restrict__ W1l,
                            short* __restrict__ W2h, short* __restrict__ W2l,
                            ushort* __restrict__ nbh, ushort* __restrict__ nbl) {
    int b = blockIdx.x, t = threadIdx.x;
    if (b < 128) {
        wsplit_one(Ws0, Wn0, W0h, W0l, 128, b * 256 + t);
    } else if (b < 256) {
        wsplit_one(Ws1, Wn1, W1h, W1l, 128, (b - 128) * 256 + t);
    } else if (b < 320) {
        wsplit_one(Ws2, Wn2, W2h, W2l, 64, (b - 256) * 256 + t);
    } else {
        int i = (b - 320) * 256 + t;          // 4 floats per thread
        if (i < N_NODES * 32) {
            f32x4 v = *(const f32x4*)(x + (size_t)i * 4);
            ushort4 h4, l4;
            ushort hb;
            hb = f2bf(v[0]); h4.x = hb; l4.x = f2bf(v[0] - bf2f(hb));
            hb = f2bf(v[1]); h4.y = hb; l4.y = f2bf(v[1] - bf2f(hb));
            hb = f2bf(v[2]); h4.z = hb; l4.z = f2bf(v[2] - bf2f(hb));
            hb = f2bf(v[3]); h4.w = hb; l4.w = f2bf(v[3] - bf2f(hb));
            *(ushort4*)(nbh + (size_t)i * 4) = h4;
            *(ushort4*)(nbl + (size_t)i * 4) = l4;
        }
    }
}

// ---------------------------------------------------------------- aggregate (bf16 gather)
// 32 lanes per edge-row (uint2 = 8B = 4 cols/lane); two half-waves process the
// two halves of the edge range concurrently; shfl_xor(32) reduce; hi/lo output.

__global__ __launch_bounds__(256) void aggregate_kernel(
    const ushort* __restrict__ hb, const int* __restrict__ rowptr,
    const int* __restrict__ col, const int* __restrict__ cnt,
    uint32_t* __restrict__ aggh, uint32_t* __restrict__ aggl)
{
    int node = blockIdx.x * 4 + (threadIdx.x >> 6);
    int l = threadIdx.x & 63;
    if (node >= N_NODES) return;
    const int half = l >> 5;          // 0 / 1
    const int c    = l & 31;          // uint2 chunk: cols 4c..4c+3

    int beg = rowptr[node], end = rowptr[node + 1];
    int mid = beg + ((end - beg + 1) >> 1);
    int e    = half ? mid : beg;
    int hend = half ? end : mid;

    f32x4 s = {0.f, 0.f, 0.f, 0.f};

#define ACCUM(U) do {                                                        \
        s[0] += __builtin_bit_cast(float, (U).x << 16);                      \
        s[1] += __builtin_bit_cast(float, (U).x & 0xffff0000u);              \
        s[2] += __builtin_bit_cast(float, (U).y << 16);                      \
        s[3] += __builtin_bit_cast(float, (U).y & 0xffff0000u);              \
    } while (0)

    for (; e + 3 < hend; e += 4) {
        uint2 u0 = *(const uint2*)&hb[(size_t)col[e]     * 128 + c * 4];
        uint2 u1 = *(const uint2*)&hb[(size_t)col[e + 1] * 128 + c * 4];
        uint2 u2 = *(const uint2*)&hb[(size_t)col[e + 2] * 128 + c * 4];
        uint2 u3 = *(const uint2*)&hb[(size_t)col[e + 3] * 128 + c * 4];
        ACCUM(u0); ACCUM(u1); ACCUM(u2); ACCUM(u3);
    }
    for (; e < hend; ++e) {
        uint2 u = *(const uint2*)&hb[(size_t)col[e] * 128 + c * 4];
        ACCUM(u);
    }
#undef ACCUM

    s[0] += __shfl_xor(s[0], 32);
    s[1] += __shfl_xor(s[1], 32);
    s[2] += __shfl_xor(s[2], 32);
    s[3] += __shfl_xor(s[3], 32);

    if (half == 0) {
        float dinv = 1.0f / (float)max(cnt[node], 1);
        float a0 = s[0] * dinv, a1 = s[1] * dinv, a2 = s[2] * dinv, a3 = s[3] * dinv;
        ushort h0 = f2bf(a0), h1 = f2bf(a1), h2 = f2bf(a2), h3 = f2bf(a3);
        ushort l0 = f2bf(a0 - bf2f(h0)), l1 = f2bf(a1 - bf2f(h1));
        ushort l2 = f2bf(a2 - bf2f(h2)), l3 = f2bf(a3 - bf2f(h3));
        uint2 wh = { (uint32_t)h0 | ((uint32_t)h1 << 16), (uint32_t)h2 | ((uint32_t)h3 << 16) };
        uint2 wl = { (uint32_t)l0 | ((uint32_t)l1 << 16), (uint32_t)l2 | ((uint32_t)l3 << 16) };
        ((uint2*)aggh)[(size_t)node * 32 + c] = wh;
        ((uint2*)aggl)[(size_t)node * 32 + c] = wl;
    }
}

// ---------------------------------------------------------------- combine GEMM v7
// 512 threads / 8 waves, tile 256 rows x 32 cols. Per-wave work identical to
// v5 (32 rows, 2x2 frags) but 8 waves share one B-stage: LDS 33.8KB/block ->
// 4 blocks/CU -> 32 waves/CU cap (was 16). Occupancy is the latency-hiding
// lever; register prefetch was twice defeated by the compiler (VGPR stuck 52).
// Bijective XCD mapping (196 rowblks % 8 != 0).

template <int NOUT, int CB, bool RELU, bool FINAL>
__global__ __launch_bounds__(512) void combine_mfma7(
    const ushort* __restrict__ nbh, const ushort* __restrict__ nbl,
    const ushort* __restrict__ aggh, const ushort* __restrict__ aggl,
    const short* __restrict__ Wth, const short* __restrict__ Wtl,
    const float* __restrict__ bias, float* __restrict__ out,
    ushort* __restrict__ oh, ushort* __restrict__ ol)
{
    __shared__ __attribute__((aligned(16))) short Bh[32 * 33 * 8];
    __shared__ __attribute__((aligned(16))) short Bl[32 * 33 * 8];

    // ---- bijective XCD-aware mapping: 196 = 4*25 + 4*24
    const int id  = blockIdx.x;          // grid = 8 * 25 * CB
    const int xcd = id & 7;
    const int k   = id >> 3;
    const int rb  = k / CB;
    const int cnt_x = (xcd < 4) ? 25 : 24;
    if (rb >= cnt_x) return;             // uniform across block
    const int base  = (xcd < 4) ? xcd * 25 : 100 + (xcd - 4) * 24;
    const int row0    = (base + rb) * 256;
    const int colbase = (k % CB) * 32;

    const int tid  = threadIdx.x;
    const int lane = tid & 63;
    const int wave = tid >> 6;           // 0..7
    const int rr = lane & 15;
    const int kq = lane >> 4;            // 0..3

    const size_t arow0 = (size_t)(row0 + wave * 32 + rr) * 128;
    const size_t arow1 = arow0 + (size_t)16 * 128;

    bf16x8 ah[3][2], al[3][2];           // [buffer][mi], all indices literal

#define LOADA(KS, P) do {                                                   \
        const ushort* bh_ = ((KS) < 4) ? nbh : aggh;                        \
        const ushort* bl_ = ((KS) < 4) ? nbl : aggl;                        \
        const int kf_ = ((KS) & 3) * 32 + kq * 8;                           \
        ah[P][0] = *(const bf16x8*)(bh_ + arow0 + kf_);                     \
        al[P][0] = *(const bf16x8*)(bl_ + arow0 + kf_);                     \
        ah[P][1] = *(const bf16x8*)(bh_ + arow1 + kf_);                     \
        al[P][1] = *(const bf16x8*)(bl_ + arow1 + kf_);                     \
    } while (0)

#define COMPUTE(KS, P) do {                                                 \
        _Pragma("unroll")                                                   \
        for (int nj = 0; nj < 2; ++nj) {                                    \
            int colL = nj * 16 + rr;                                        \
            bf16x8 bh = ((const bf16x8*)Bh)[colL * 33 + (KS) * 4 + kq];     \
            bf16x8 bl = ((const bf16x8*)Bl)[colL * 33 + (KS) * 4 + kq];     \
            acc[0][nj] = __builtin_amdgcn_mfma_f32_16x16x32_bf16(ah[P][0], bh, acc[0][nj], 0, 0, 0); \
            acc[0][nj] = __builtin_amdgcn_mfma_f32_16x16x32_bf16(al[P][0], bh, acc[0][nj], 0, 0, 0); \
            acc[0][nj] = __builtin_amdgcn_mfma_f32_16x16x32_bf16(ah[P][0], bl, acc[0][nj], 0, 0, 0); \
            acc[1][nj] = __builtin_amdgcn_mfma_f32_16x16x32_bf16(ah[P][1], bh, acc[1][nj], 0, 0, 0); \
            acc[1][nj] = __builtin_amdgcn_mfma_f32_16x16x32_bf16(al[P][1], bh, acc[1][nj], 0, 0, 0); \
            acc[1][nj] = __builtin_amdgcn_mfma_f32_16x16x32_bf16(ah[P][1], bl, acc[1][nj], 0, 0, 0); \
        }                                                                   \
    } while (0)

#define SB __builtin_amdgcn_sched_barrier(0)

    LOADA(0, 0);
    LOADA(1, 1);

    // ---- stage B once (512 threads: 2 chunks each per array)
    {
        int col = tid >> 4;
        int kc0 = (tid & 15) * 2;
        const short* gh = Wth + (size_t)(colbase + col) * 256 + kc0 * 8;
        const short* gl = Wtl + (size_t)(colbase + col) * 256 + kc0 * 8;
        #pragma unroll
        for (int j = 0; j < 2; ++j) {
            ((bf16x8*)Bh)[col * 33 + kc0 + j] = *(const bf16x8*)(gh + j * 8);
            ((bf16x8*)Bl)[col * 33 + kc0 + j] = *(const bf16x8*)(gl + j * 8);
        }
    }

    f32x4 acc[2][2];
    #pragma unroll
    for (int i = 0; i < 2; ++i)
        #pragma unroll
        for (int j = 0; j < 2; ++j)
            acc[i][j] = (f32x4){0.f, 0.f, 0.f, 0.f};

    __syncthreads();

    LOADA(2, 2); SB; COMPUTE(0, 0);
    LOADA(3, 0); SB; COMPUTE(1, 1);
    LOADA(4, 1); SB; COMPUTE(2, 2);
    LOADA(5, 2); SB; COMPUTE(3, 0);
    LOADA(6, 0); SB; COMPUTE(4, 1);
    LOADA(7, 1); SB; COMPUTE(5, 2);
    COMPUTE(6, 0);
    COMPUTE(7, 1);

#undef LOADA
#undef COMPUTE
#undef SB

    // ---- epilogue: D col=lane&15, row=(lane>>4)*4+r
    const int rg = lane >> 4;
    #pragma unroll
    for (int nj = 0; nj < 2; ++nj) {
        int colg = colbase + nj * 16 + rr;
        float bv = bias[colg];
        #pragma unroll
        for (int mi = 0; mi < 2; ++mi) {
            #pragma unroll
            for (int r = 0; r < 4; ++r) {
                int row = row0 + wave * 32 + mi * 16 + rg * 4 + r;
                if (row < N_NODES) {
                    float v = acc[mi][nj][r] + bv;
                    if (RELU) v = fmaxf(v, 0.f);
                    if (FINAL) {
                        out[(size_t)row * NOUT + colg] = v;
                    } else {
                        ushort hb = f2bf(v);
                        oh[(size_t)row * NOUT + colg] = hb;
                        ol[(size_t)row * NOUT + colg] = f2bf(v - bf2f(hb));
                    }
                }
            }
        }
    }
}

// ---------------------------------------------------------------- launch

extern "C" void kernel_launch(void* const* d_in, const int* in_sizes, int n_in,
                              void* d_out, int out_size, void* d_ws, size_t ws_size,
                              hipStream_t stream) {
    const float* x   = (const float*)d_in[0];
    const int*   src = (const int*)d_in[1];
    const int*   dst = (const int*)d_in[2];
    const float* Ws0 = (const float*)d_in[3];
    const float* Wn0 = (const float*)d_in[4];
    const float* b0  = (const float*)d_in[5];
    const float* Ws1 = (const float*)d_in[6];
    const float* Wn1 = (const float*)d_in[7];
    const float* b1  = (const float*)d_in[8];
    const float* Ws2 = (const float*)d_in[9];
    const float* Wn2 = (const float*)d_in[10];
    const float* b2  = (const float*)d_in[11];
    float* out = (float*)d_out;

    char* p = (char*)d_ws;
    auto alloc = [&](size_t bytes) {
        char* r = p;
        p += (bytes + 255) & ~(size_t)255;
        return r;
    };
    int*      cnt      = (int*)alloc((size_t)N_NODES * 4);
    int*      cursor   = (int*)alloc((size_t)N_NODES * 4);
    int*      rowptr   = (int*)alloc((size_t)(N_NODES + 1) * 4);
    int*      col      = (int*)alloc((size_t)N_EDGES * 4);
    int*      partials = (int*)alloc((size_t)NPART * 4);
    int*      offsets  = (int*)alloc((size_t)NPART * 4);
    uint32_t* aggh     = (uint32_t*)alloc((size_t)PADROWS * 64 * 4);
    uint32_t* aggl     = (uint32_t*)alloc((size_t)PADROWS * 64 * 4);
    ushort*   nbh0     = (ushort*)alloc((size_t)PADROWS * 128 * 2);
    ushort*   nbl0     = (ushort*)alloc((size_t)PADROWS * 128 * 2);
    ushort*   nbh1     = (ushort*)alloc((size_t)PADROWS * 128 * 2);
    ushort*   nbl1     = (ushort*)alloc((size_t)PADROWS * 128 * 2);
    short*    Wt0_hi   = (short*)alloc((size_t)128 * 256 * 2);
    short*    Wt0_lo   = (short*)alloc((size_t)128 * 256 * 2);
    short*    Wt1_hi   = (short*)alloc((size_t)128 * 256 * 2);
    short*    Wt1_lo   = (short*)alloc((size_t)128 * 256 * 2);
    short*    Wt2_hi   = (short*)alloc((size_t)64 * 256 * 2);
    short*    Wt2_lo   = (short*)alloc((size_t)64 * 256 * 2);

    // CSR build
    zero2_kernel<<<NPART, 256, 0, stream>>>(cnt, cursor);
    count_kernel<<<(N_EDGES + 255) / 256, 256, 0, stream>>>(dst, cnt);
    scan_part <<<NPART, 256, 0, stream>>>(cnt, partials);
    scan_mid  <<<1, 256, 0, stream>>>(partials, offsets);
    scan_final<<<NPART, 256, 0, stream>>>(cnt, offsets, rowptr);
    fill_kernel<<<(N_EDGES + 255) / 256, 256, 0, stream>>>(src, dst, rowptr, cursor, col);

    // weight prep + x split (single launch)
    prep_kernel<<<320 + (N_NODES * 32 + 255) / 256, 256, 0, stream>>>(
        Ws0, Wn0, Ws1, Wn1, Ws2, Wn2, x,
        Wt0_hi, Wt0_lo, Wt1_hi, Wt1_lo, Wt2_hi, Wt2_lo, nbh0, nbl0);

    const int AGB = (N_NODES + 3) / 4;        // 12500

    // layer 0
    aggregate_kernel<<<AGB, 256, 0, stream>>>(nbh0, rowptr, col, cnt, aggh, aggl);
    combine_mfma7<128, 4, true, false><<<8 * 25 * 4, 512, 0, stream>>>(
        nbh0, nbl0, (const ushort*)aggh, (const ushort*)aggl, Wt0_hi, Wt0_lo, b0, nullptr, nbh1, nbl1);
    // layer 1
    aggregate_kernel<<<AGB, 256, 0, stream>>>(nbh1, rowptr, col, cnt, aggh, aggl);
    combine_mfma7<128, 4, true, false><<<8 * 25 * 4, 512, 0, stream>>>(
        nbh1, nbl1, (const ushort*)aggh, (const ushort*)aggl, Wt1_hi, Wt1_lo, b1, nullptr, nbh0, nbl0);
    // layer 2
    aggregate_kernel<<<AGB, 256, 0, stream>>>(nbh0, rowptr, col, cnt, aggh, aggl);
    combine_mfma7<64, 2, false, true><<<8 * 25 * 2, 512, 0, stream>>>(
        nbh0, nbl0, (const ushort*)aggh, (const ushort*)aggl, Wt2_hi, Wt2_lo, b2, out, nullptr, nullptr);
}

// Round 10
// 224.960 us; speedup vs baseline: 1.1938x; 1.1938x over previous
//
#include <hip/hip_runtime.h>

#define N_NODES 50000
#define PADROWS 50176   // 196*256, branchless A loads (256-row tiles)
#define N_EDGES 600000
#define NPART 196   // ceil(50000/256)

using f32x4  = __attribute__((ext_vector_type(4))) float;
using bf16x8 = __attribute__((ext_vector_type(8))) short;

__device__ inline ushort f2bf(float f) {
    uint32_t u = __builtin_bit_cast(uint32_t, f);
    uint32_t r = (u + 0x7FFFu + ((u >> 16) & 1u)) >> 16;
    return (ushort)r;
}
__device__ inline float bf2f(ushort h) {
    uint32_t u = ((uint32_t)h) << 16;
    return __builtin_bit_cast(float, u);
}

// ---------------------------------------------------------------- zero

__global__ void zero2_kernel(int* __restrict__ a, int* __restrict__ b) {
    int i = blockIdx.x * 256 + threadIdx.x;
    if (i < N_NODES) { a[i] = 0; b[i] = 0; }
}

// ---------------------------------------------------------------- CSR build

__global__ void count_kernel(const int* __restrict__ dst, int* __restrict__ cnt) {
    int e = blockIdx.x * blockDim.x + threadIdx.x;
    if (e < N_EDGES) atomicAdd(&cnt[dst[e]], 1);
}

__global__ void scan_part(const int* __restrict__ cnt, int* __restrict__ partials) {
    __shared__ int sm[256];
    int b = blockIdx.x, t = threadIdx.x;
    int i = b * 256 + t;
    sm[t] = (i < N_NODES) ? cnt[i] : 0;
    __syncthreads();
    for (int off = 128; off > 0; off >>= 1) {
        if (t < off) sm[t] += sm[t + off];
        __syncthreads();
    }
    if (t == 0) partials[b] = sm[0];
}

__global__ void scan_mid(const int* __restrict__ partials, int* __restrict__ offsets) {
    __shared__ int sm[256];
    int t = threadIdx.x;
    int v = (t < NPART) ? partials[t] : 0;
    sm[t] = v;
    __syncthreads();
    for (int off = 1; off < 256; off <<= 1) {
        int u = (t >= off) ? sm[t - off] : 0;
        __syncthreads();
        sm[t] += u;
        __syncthreads();
    }
    if (t < NPART) offsets[t] = sm[t] - v;   // exclusive prefix
}

__global__ void scan_final(const int* __restrict__ cnt, const int* __restrict__ offsets,
                           int* __restrict__ rowptr) {
    __shared__ int sm[256];
    int b = blockIdx.x, t = threadIdx.x;
    int i = b * 256 + t;
    int v = (i < N_NODES) ? cnt[i] : 0;
    sm[t] = v;
    __syncthreads();
    for (int off = 1; off < 256; off <<= 1) {
        int u = (t >= off) ? sm[t - off] : 0;
        __syncthreads();
        sm[t] += u;
        __syncthreads();
    }
    if (i < N_NODES) rowptr[i + 1] = sm[t] + offsets[b];
    if (i == 0) rowptr[0] = 0;
}

__global__ void fill_kernel(const int* __restrict__ src, const int* __restrict__ dst,
                            const int* __restrict__ rowptr, int* __restrict__ cursor,
                            int* __restrict__ col) {
    int e = blockIdx.x * blockDim.x + threadIdx.x;
    if (e < N_EDGES) {
        int d = dst[e];
        int pos = atomicAdd(&cursor[d], 1);
        col[rowptr[d] + pos] = src[e];
    }
}

// ---------------------------------------------------------------- prep: 3x wsplit (B keeps hi/lo) + x cast (bf16 only)

__device__ inline void wsplit_one(const float* __restrict__ Ws, const float* __restrict__ Wn,
                                  short* __restrict__ Wh, short* __restrict__ Wl,
                                  int nout, int idx) {
    int c = idx >> 8, k = idx & 255;
    float v = (k < 128) ? Ws[(size_t)k * nout + c] : Wn[(size_t)(k - 128) * nout + c];
    ushort hi = f2bf(v);
    Wh[idx] = (short)hi;
    Wl[idx] = (short)f2bf(v - bf2f(hi));
}

__global__ void prep_kernel(const float* __restrict__ Ws0, const float* __restrict__ Wn0,
                            const float* __restrict__ Ws1, const float* __restrict__ Wn1,
                            const float* __restrict__ Ws2, const float* __restrict__ Wn2,
                            const float* __restrict__ x,
                            short* __restrict__ W0h, short* __restrict__ W0l,
                            short* __restrict__ W1h, short* __restrict__ W1l,
                            short* __restrict__ W2h, short* __restrict__ W2l,
                            ushort* __restrict__ nbh) {
    int b = blockIdx.x, t = threadIdx.x;
    if (b < 128) {
        wsplit_one(Ws0, Wn0, W0h, W0l, 128, b * 256 + t);
    } else if (b < 256) {
        wsplit_one(Ws1, Wn1, W1h, W1l, 128, (b - 128) * 256 + t);
    } else if (b < 320) {
        wsplit_one(Ws2, Wn2, W2h, W2l, 64, (b - 256) * 256 + t);
    } else {
        int i = (b - 320) * 256 + t;          // 4 floats per thread
        if (i < N_NODES * 32) {
            f32x4 v = *(const f32x4*)(x + (size_t)i * 4);
            ushort4 h4;
            h4.x = f2bf(v[0]); h4.y = f2bf(v[1]);
            h4.z = f2bf(v[2]); h4.w = f2bf(v[3]);
            *(ushort4*)(nbh + (size_t)i * 4) = h4;
        }
    }
}

// ---------------------------------------------------------------- aggregate (bf16 gather -> bf16 agg)
// 32 lanes per edge-row (uint2 = 4 cols/lane); half-waves split the edge range;
// shfl_xor(32) reduce; f32 accumulate; plain bf16 output (A-side is bf16 now).

__global__ __launch_bounds__(256) void aggregate_kernel(
    const ushort* __restrict__ hb, const int* __restrict__ rowptr,
    const int* __restrict__ col, const int* __restrict__ cnt,
    uint32_t* __restrict__ aggh)
{
    int node = blockIdx.x * 4 + (threadIdx.x >> 6);
    int l = threadIdx.x & 63;
    if (node >= N_NODES) return;
    const int half = l >> 5;          // 0 / 1
    const int c    = l & 31;          // uint2 chunk: cols 4c..4c+3

    int beg = rowptr[node], end = rowptr[node + 1];
    int mid = beg + ((end - beg + 1) >> 1);
    int e    = half ? mid : beg;
    int hend = half ? end : mid;

    f32x4 s = {0.f, 0.f, 0.f, 0.f};

#define ACCUM(U) do {                                                        \
        s[0] += __builtin_bit_cast(float, (U).x << 16);                      \
        s[1] += __builtin_bit_cast(float, (U).x & 0xffff0000u);              \
        s[2] += __builtin_bit_cast(float, (U).y << 16);                      \
        s[3] += __builtin_bit_cast(float, (U).y & 0xffff0000u);              \
    } while (0)

    for (; e + 3 < hend; e += 4) {
        uint2 u0 = *(const uint2*)&hb[(size_t)col[e]     * 128 + c * 4];
        uint2 u1 = *(const uint2*)&hb[(size_t)col[e + 1] * 128 + c * 4];
        uint2 u2 = *(const uint2*)&hb[(size_t)col[e + 2] * 128 + c * 4];
        uint2 u3 = *(const uint2*)&hb[(size_t)col[e + 3] * 128 + c * 4];
        ACCUM(u0); ACCUM(u1); ACCUM(u2); ACCUM(u3);
    }
    for (; e < hend; ++e) {
        uint2 u = *(const uint2*)&hb[(size_t)col[e] * 128 + c * 4];
        ACCUM(u);
    }
#undef ACCUM

    s[0] += __shfl_xor(s[0], 32);
    s[1] += __shfl_xor(s[1], 32);
    s[2] += __shfl_xor(s[2], 32);
    s[3] += __shfl_xor(s[3], 32);

    if (half == 0) {
        float dinv = 1.0f / (float)max(cnt[node], 1);
        ushort h0 = f2bf(s[0] * dinv), h1 = f2bf(s[1] * dinv);
        ushort h2 = f2bf(s[2] * dinv), h3 = f2bf(s[3] * dinv);
        uint2 wh = { (uint32_t)h0 | ((uint32_t)h1 << 16), (uint32_t)h2 | ((uint32_t)h3 << 16) };
        ((uint2*)aggh)[(size_t)node * 32 + c] = wh;
    }
}

// ---------------------------------------------------------------- combine GEMM v8
// out[n,j] = relu([h|agg][n,:] @ Wcat[:,j] + b), K=256.
// A side PLAIN bf16 (h and agg — matches gather-path precision, 2x less load
// traffic, 2/3 the MFMAs); B side hi/lo (weights keep f32 precision):
//   acc += ah*bh + ah*bl   (2 MFMA per fragment pair)
// 512 thr / 8 waves, 256row x 32col tile, B in LDS once, no k-loop barriers,
// bijective XCD mapping (196 = 4*25 + 4*24).

template <int NOUT, int CB, bool RELU, bool FINAL>
__global__ __launch_bounds__(512) void combine_mfma8(
    const ushort* __restrict__ nbh, const ushort* __restrict__ aggh,
    const short* __restrict__ Wth, const short* __restrict__ Wtl,
    const float* __restrict__ bias, float* __restrict__ out,
    ushort* __restrict__ oh)
{
    __shared__ __attribute__((aligned(16))) short Bh[32 * 33 * 8];
    __shared__ __attribute__((aligned(16))) short Bl[32 * 33 * 8];

    // ---- bijective XCD-aware mapping: 196 = 4*25 + 4*24
    const int id  = blockIdx.x;          // grid = 8 * 25 * CB
    const int xcd = id & 7;
    const int k   = id >> 3;
    const int rb  = k / CB;
    const int cnt_x = (xcd < 4) ? 25 : 24;
    if (rb >= cnt_x) return;             // uniform across block
    const int base  = (xcd < 4) ? xcd * 25 : 100 + (xcd - 4) * 24;
    const int row0    = (base + rb) * 256;
    const int colbase = (k % CB) * 32;

    const int tid  = threadIdx.x;
    const int lane = tid & 63;
    const int wave = tid >> 6;           // 0..7
    const int rr = lane & 15;
    const int kq = lane >> 4;            // 0..3

    const size_t arow0 = (size_t)(row0 + wave * 32 + rr) * 128;
    const size_t arow1 = arow0 + (size_t)16 * 128;

    bf16x8 ah[3][2];                     // [buffer][mi], literal indices

#define LOADA(KS, P) do {                                                   \
        const ushort* bh_ = ((KS) < 4) ? nbh : aggh;                        \
        const int kf_ = ((KS) & 3) * 32 + kq * 8;                           \
        ah[P][0] = *(const bf16x8*)(bh_ + arow0 + kf_);                     \
        ah[P][1] = *(const bf16x8*)(bh_ + arow1 + kf_);                     \
    } while (0)

#define COMPUTE(KS, P) do {                                                 \
        _Pragma("unroll")                                                   \
        for (int nj = 0; nj < 2; ++nj) {                                    \
            int colL = nj * 16 + rr;                                        \
            bf16x8 bh = ((const bf16x8*)Bh)[colL * 33 + (KS) * 4 + kq];     \
            bf16x8 bl = ((const bf16x8*)Bl)[colL * 33 + (KS) * 4 + kq];     \
            acc[0][nj] = __builtin_amdgcn_mfma_f32_16x16x32_bf16(ah[P][0], bh, acc[0][nj], 0, 0, 0); \
            acc[0][nj] = __builtin_amdgcn_mfma_f32_16x16x32_bf16(ah[P][0], bl, acc[0][nj], 0, 0, 0); \
            acc[1][nj] = __builtin_amdgcn_mfma_f32_16x16x32_bf16(ah[P][1], bh, acc[1][nj], 0, 0, 0); \
            acc[1][nj] = __builtin_amdgcn_mfma_f32_16x16x32_bf16(ah[P][1], bl, acc[1][nj], 0, 0, 0); \
        }                                                                   \
    } while (0)

#define SB __builtin_amdgcn_sched_barrier(0)

    LOADA(0, 0);
    LOADA(1, 1);

    // ---- stage B once (512 threads: 2 chunks each per array)
    {
        int col = tid >> 4;
        int kc0 = (tid & 15) * 2;
        const short* gh = Wth + (size_t)(colbase + col) * 256 + kc0 * 8;
        const short* gl = Wtl + (size_t)(colbase + col) * 256 + kc0 * 8;
        #pragma unroll
        for (int j = 0; j < 2; ++j) {
            ((bf16x8*)Bh)[col * 33 + kc0 + j] = *(const bf16x8*)(gh + j * 8);
            ((bf16x8*)Bl)[col * 33 + kc0 + j] = *(const bf16x8*)(gl + j * 8);
        }
    }

    f32x4 acc[2][2];
    #pragma unroll
    for (int i = 0; i < 2; ++i)
        #pragma unroll
        for (int j = 0; j < 2; ++j)
            acc[i][j] = (f32x4){0.f, 0.f, 0.f, 0.f};

    __syncthreads();

    LOADA(2, 2); SB; COMPUTE(0, 0);
    LOADA(3, 0); SB; COMPUTE(1, 1);
    LOADA(4, 1); SB; COMPUTE(2, 2);
    LOADA(5, 2); SB; COMPUTE(3, 0);
    LOADA(6, 0); SB; COMPUTE(4, 1);
    LOADA(7, 1); SB; COMPUTE(5, 2);
    COMPUTE(6, 0);
    COMPUTE(7, 1);

#undef LOADA
#undef COMPUTE
#undef SB

    // ---- epilogue: D col=lane&15, row=(lane>>4)*4+r
    const int rg = lane >> 4;
    #pragma unroll
    for (int nj = 0; nj < 2; ++nj) {
        int colg = colbase + nj * 16 + rr;
        float bv = bias[colg];
        #pragma unroll
        for (int mi = 0; mi < 2; ++mi) {
            #pragma unroll
            for (int r = 0; r < 4; ++r) {
                int row = row0 + wave * 32 + mi * 16 + rg * 4 + r;
                if (row < N_NODES) {
                    float v = acc[mi][nj][r] + bv;
                    if (RELU) v = fmaxf(v, 0.f);
                    if (FINAL) out[(size_t)row * NOUT + colg] = v;
                    else       oh[(size_t)row * NOUT + colg] = f2bf(v);
                }
            }
        }
    }
}

// ---------------------------------------------------------------- launch

extern "C" void kernel_launch(void* const* d_in, const int* in_sizes, int n_in,
                              void* d_out, int out_size, void* d_ws, size_t ws_size,
                              hipStream_t stream) {
    const float* x   = (const float*)d_in[0];
    const int*   src = (const int*)d_in[1];
    const int*   dst = (const int*)d_in[2];
    const float* Ws0 = (const float*)d_in[3];
    const float* Wn0 = (const float*)d_in[4];
    const float* b0  = (const float*)d_in[5];
    const float* Ws1 = (const float*)d_in[6];
    const float* Wn1 = (const float*)d_in[7];
    const float* b1  = (const float*)d_in[8];
    const float* Ws2 = (const float*)d_in[9];
    const float* Wn2 = (const float*)d_in[10];
    const float* b2  = (const float*)d_in[11];
    float* out = (float*)d_out;

    char* p = (char*)d_ws;
    auto alloc = [&](size_t bytes) {
        char* r = p;
        p += (bytes + 255) & ~(size_t)255;
        return r;
    };
    int*      cnt      = (int*)alloc((size_t)N_NODES * 4);
    int*      cursor   = (int*)alloc((size_t)N_NODES * 4);
    int*      rowptr   = (int*)alloc((size_t)(N_NODES + 1) * 4);
    int*      col      = (int*)alloc((size_t)N_EDGES * 4);
    int*      partials = (int*)alloc((size_t)NPART * 4);
    int*      offsets  = (int*)alloc((size_t)NPART * 4);
    uint32_t* aggh     = (uint32_t*)alloc((size_t)PADROWS * 64 * 4);
    ushort*   nbh0     = (ushort*)alloc((size_t)PADROWS * 128 * 2);
    ushort*   nbh1     = (ushort*)alloc((size_t)PADROWS * 128 * 2);
    short*    Wt0_hi   = (short*)alloc((size_t)128 * 256 * 2);
    short*    Wt0_lo   = (short*)alloc((size_t)128 * 256 * 2);
    short*    Wt1_hi   = (short*)alloc((size_t)128 * 256 * 2);
    short*    Wt1_lo   = (short*)alloc((size_t)128 * 256 * 2);
    short*    Wt2_hi   = (short*)alloc((size_t)64 * 256 * 2);
    short*    Wt2_lo   = (short*)alloc((size_t)64 * 256 * 2);

    // CSR build
    zero2_kernel<<<NPART, 256, 0, stream>>>(cnt, cursor);
    count_kernel<<<(N_EDGES + 255) / 256, 256, 0, stream>>>(dst, cnt);
    scan_part <<<NPART, 256, 0, stream>>>(cnt, partials);
    scan_mid  <<<1, 256, 0, stream>>>(partials, offsets);
    scan_final<<<NPART, 256, 0, stream>>>(cnt, offsets, rowptr);
    fill_kernel<<<(N_EDGES + 255) / 256, 256, 0, stream>>>(src, dst, rowptr, cursor, col);

    // weight prep (hi/lo) + x cast (bf16), single launch
    prep_kernel<<<320 + (N_NODES * 32 + 255) / 256, 256, 0, stream>>>(
        Ws0, Wn0, Ws1, Wn1, Ws2, Wn2, x,
        Wt0_hi, Wt0_lo, Wt1_hi, Wt1_lo, Wt2_hi, Wt2_lo, nbh0);

    const int AGB = (N_NODES + 3) / 4;        // 12500

    // layer 0
    aggregate_kernel<<<AGB, 256, 0, stream>>>(nbh0, rowptr, col, cnt, aggh);
    combine_mfma8<128, 4, true, false><<<8 * 25 * 4, 512, 0, stream>>>(
        nbh0, (const ushort*)aggh, Wt0_hi, Wt0_lo, b0, nullptr, nbh1);
    // layer 1
    aggregate_kernel<<<AGB, 256, 0, stream>>>(nbh1, rowptr, col, cnt, aggh);
    combine_mfma8<128, 4, true, false><<<8 * 25 * 4, 512, 0, stream>>>(
        nbh1, (const ushort*)aggh, Wt1_hi, Wt1_lo, b1, nullptr, nbh0);
    // layer 2
    aggregate_kernel<<<AGB, 256, 0, stream>>>(nbh0, rowptr, col, cnt, aggh);
    combine_mfma8<64, 2, false, true><<<8 * 25 * 2, 512, 0, stream>>>(
        nbh0, (const ushort*)aggh, Wt2_hi, Wt2_lo, b2, out, nullptr);
}